// Round 2
// baseline (1181.147 us; speedup 1.0000x reference)
//
#include <hip/hip_runtime.h>

#define NN 100000
#define NE 600000
#define DD 128

typedef __bf16 bf16x8 __attribute__((ext_vector_type(8)));
typedef float f32x4 __attribute__((ext_vector_type(4)));
typedef unsigned short ushort8 __attribute__((ext_vector_type(8)));

static __device__ __forceinline__ unsigned short f2bf(float f) {
    return __builtin_bit_cast(unsigned short, (__bf16)f);
}

// Transpose W1/W2 into ws as bf16: wt[n][k] = W[k][n]  (contiguous-in-k B-fragments)
__global__ void prep_w_kernel(const float* __restrict__ W1, const float* __restrict__ W2,
                              unsigned short* __restrict__ w1t, unsigned short* __restrict__ w2t) {
    int t = blockIdx.x * blockDim.x + threadIdx.x;   // 16384 threads
    int k = t >> 7, n = t & 127;
    w1t[n * DD + k] = f2bf(W1[k * DD + n]);
    w2t[n * DD + k] = f2bf(W2[k * DD + n]);
}

// m[dst] += x[src] — 32 threads per edge, 4 floats each, native f32 atomics
__global__ void scatter_kernel(const float* __restrict__ x, const int* __restrict__ ei,
                               float* __restrict__ m) {
    int t = blockIdx.x * blockDim.x + threadIdx.x;   // NE*32 threads
    int e = t >> 5;
    int c = (t & 31) * 4;
    if (e >= NE) return;
    int src = ei[e];
    int dst = ei[NE + e];
    float4 v = *(const float4*)(x + (size_t)src * DD + c);
    float* mp = m + (size_t)dst * DD + c;
    unsafeAtomicAdd(mp + 0, v.x);
    unsafeAtomicAdd(mp + 1, v.y);
    unsafeAtomicAdd(mp + 2, v.z);
    unsafeAtomicAdd(mp + 3, v.w);
}

// Fused: h0 = x + m; h1 = relu(h0@W1+b1); h = h1@W2+b2; out = LN(h)*gamma+beta
// Block = 256 threads (4 waves), 64 nodes/block, wave w owns rows [blk*64+w*16, +16).
// MFMA 16x16x32 bf16. A-frag: row = lane&15, k = (lane>>4)*8+i.
// C/D: col = lane&15, row = (lane>>4)*4 + reg  [verified mapping].
__launch_bounds__(256)
__global__ void fused_mlp_ln_kernel(const float* __restrict__ x, const float* __restrict__ m,
                                    const unsigned short* __restrict__ w1t,
                                    const unsigned short* __restrict__ w2t,
                                    const float* __restrict__ b1, const float* __restrict__ b2,
                                    const float* __restrict__ gamma, const float* __restrict__ beta,
                                    float* __restrict__ out) {
    // per-wave H1 buffer, stride 136 (=272B, 16B-aligned rows, bank-spread)
    __shared__ __align__(16) unsigned short h1[4][16][136];

    const int tid  = threadIdx.x;
    const int w    = tid >> 6;        // wave 0..3
    const int l    = tid & 63;
    const int lcol = l & 15;
    const int g    = l >> 4;          // 0..3
    const int m0   = blockIdx.x * 64 + w * 16;

    // ---- A fragments: bf16(x + m), direct from global ----
    int arow = m0 + lcol;
    if (arow >= NN) arow = NN - 1;    // clamp (uniform barrier participation)
    const float* xr = x + (size_t)arow * DD;
    const float* mr = m + (size_t)arow * DD;
    bf16x8 afrag[4];
    #pragma unroll
    for (int t = 0; t < 4; ++t) {
        int k0 = t * 32 + g * 8;
        float4 xa = *(const float4*)(xr + k0);
        float4 xb = *(const float4*)(xr + k0 + 4);
        float4 ma = *(const float4*)(mr + k0);
        float4 mb = *(const float4*)(mr + k0 + 4);
        bf16x8 a;
        a[0] = (__bf16)(xa.x + ma.x); a[1] = (__bf16)(xa.y + ma.y);
        a[2] = (__bf16)(xa.z + ma.z); a[3] = (__bf16)(xa.w + ma.w);
        a[4] = (__bf16)(xb.x + mb.x); a[5] = (__bf16)(xb.y + mb.y);
        a[6] = (__bf16)(xb.z + mb.z); a[7] = (__bf16)(xb.w + mb.w);
        afrag[t] = a;
    }

    // ---- GEMM1: acc = h0 @ W1 + b1 ----
    f32x4 acc[8];
    #pragma unroll
    for (int nt = 0; nt < 8; ++nt) {
        float bv = b1[nt * 16 + lcol];
        acc[nt] = (f32x4){bv, bv, bv, bv};
    }
    #pragma unroll
    for (int t = 0; t < 4; ++t) {
        int k0 = t * 32 + g * 8;
        #pragma unroll
        for (int nt = 0; nt < 8; ++nt) {
            ushort8 bu = *(const ushort8*)(w1t + (size_t)(nt * 16 + lcol) * DD + k0);
            acc[nt] = __builtin_amdgcn_mfma_f32_16x16x32_bf16(
                afrag[t], __builtin_bit_cast(bf16x8, bu), acc[nt], 0, 0, 0);
        }
    }

    // ---- ReLU -> per-wave LDS (transpose exchange for GEMM2 A-frags) ----
    #pragma unroll
    for (int nt = 0; nt < 8; ++nt)
        #pragma unroll
        for (int r = 0; r < 4; ++r) {
            float v = fmaxf(acc[nt][r], 0.f);
            h1[w][g * 4 + r][nt * 16 + lcol] = f2bf(v);
        }
    __syncthreads();

    bf16x8 a2[4];
    #pragma unroll
    for (int t = 0; t < 4; ++t) {
        int k0 = t * 32 + g * 8;
        a2[t] = __builtin_bit_cast(bf16x8, *(const ushort8*)(&h1[w][lcol][k0]));
    }

    // ---- GEMM2: acc = h1 @ W2 + b2 ----
    #pragma unroll
    for (int nt = 0; nt < 8; ++nt) {
        float bv = b2[nt * 16 + lcol];
        acc[nt] = (f32x4){bv, bv, bv, bv};
    }
    #pragma unroll
    for (int t = 0; t < 4; ++t) {
        #pragma unroll
        for (int nt = 0; nt < 8; ++nt) {
            ushort8 bu = *(const ushort8*)(w2t + (size_t)(nt * 16 + lcol) * DD + (t * 32 + g * 8));
            acc[nt] = __builtin_amdgcn_mfma_f32_16x16x32_bf16(
                a2[t], __builtin_bit_cast(bf16x8, bu), acc[nt], 0, 0, 0);
        }
    }

    // ---- LayerNorm over feature dim + store ----
    float gmm[8], bta[8];
    #pragma unroll
    for (int nt = 0; nt < 8; ++nt) {
        gmm[nt] = gamma[nt * 16 + lcol];
        bta[nt] = beta[nt * 16 + lcol];
    }
    #pragma unroll
    for (int r = 0; r < 4; ++r) {
        int row = m0 + g * 4 + r;
        float s = 0.f, s2 = 0.f;
        #pragma unroll
        for (int nt = 0; nt < 8; ++nt) {
            float v = acc[nt][r];
            s += v; s2 += v * v;
        }
        // row lives in one 16-lane group -> butterfly within group
        #pragma unroll
        for (int msk = 1; msk < 16; msk <<= 1) {
            s  += __shfl_xor(s,  msk);
            s2 += __shfl_xor(s2, msk);
        }
        float mu  = s * (1.f / 128.f);
        float var = s2 * (1.f / 128.f) - mu * mu;
        float rs  = rsqrtf(var + 1e-5f);
        if (row < NN) {
            float* op = out + (size_t)row * DD;
            #pragma unroll
            for (int nt = 0; nt < 8; ++nt)
                op[nt * 16 + lcol] = (acc[nt][r] - mu) * rs * gmm[nt] + bta[nt];
        }
    }
}

extern "C" void kernel_launch(void* const* d_in, const int* in_sizes, int n_in,
                              void* d_out, int out_size, void* d_ws, size_t ws_size,
                              hipStream_t stream) {
    const float* x     = (const float*)d_in[0];
    const float* W1    = (const float*)d_in[1];
    const float* b1    = (const float*)d_in[2];
    const float* W2    = (const float*)d_in[3];
    const float* b2    = (const float*)d_in[4];
    const float* gamma = (const float*)d_in[5];
    const float* beta  = (const float*)d_in[6];
    const int*   ei    = (const int*)d_in[7];
    float* out = (float*)d_out;

    // ws layout: m [NN*DD f32] | w1t [128*128 bf16] | w2t [128*128 bf16]
    float* m = (float*)d_ws;
    unsigned short* w1t = (unsigned short*)((char*)d_ws + (size_t)NN * DD * sizeof(float));
    unsigned short* w2t = w1t + DD * DD;

    hipMemsetAsync(m, 0, (size_t)NN * DD * sizeof(float), stream);
    prep_w_kernel<<<(DD * DD) / 256, 256, 0, stream>>>(W1, W2, w1t, w2t);
    scatter_kernel<<<(NE * 32) / 256, 256, 0, stream>>>(x, ei, m);
    fused_mlp_ln_kernel<<<(NN + 63) / 64, 256, 0, stream>>>(
        x, m, w1t, w2t, b1, b2, gamma, beta, out);
}

// Round 4
// 509.465 us; speedup vs baseline: 2.3184x; 2.3184x over previous
//
#include <hip/hip_runtime.h>

#define NN 100000
#define NE 600000
#define DD 128
#define CHUNK 98   // ceil(NN / 1024)

typedef __bf16 bf16x8 __attribute__((ext_vector_type(8)));
typedef float f32x4 __attribute__((ext_vector_type(4)));
typedef unsigned short ushort8 __attribute__((ext_vector_type(8)));

static __device__ __forceinline__ unsigned short f2bf(float f) {
    return __builtin_bit_cast(unsigned short, (__bf16)f);
}

// Transpose W1/W2 into ws as bf16: wt[n][k] = W[k][n]
__global__ void prep_w_kernel(const float* __restrict__ W1, const float* __restrict__ W2,
                              unsigned short* __restrict__ w1t, unsigned short* __restrict__ w2t) {
    int t = blockIdx.x * blockDim.x + threadIdx.x;   // 16384 threads
    int k = t >> 7, n = t & 127;
    w1t[n * DD + k] = f2bf(W1[k * DD + n]);
    w2t[n * DD + k] = f2bf(W2[k * DD + n]);
}

// ---- CSR build: histogram of dst degrees ----
__global__ void hist_kernel(const int* __restrict__ ei, int* __restrict__ deg) {
    int e = blockIdx.x * blockDim.x + threadIdx.x;
    if (e < NE) atomicAdd(&deg[ei[NE + e]], 1);
}

// ---- exclusive scan over deg -> row_ptr (+ cursor copy); single block, 1024 thr ----
__global__ void scan_kernel(const int* __restrict__ deg, int* __restrict__ row_ptr,
                            int* __restrict__ cursor) {
    __shared__ int sums[1024];
    int t = threadIdx.x;
    int lo = t * CHUNK; if (lo > NN) lo = NN;
    int hi = lo + CHUNK; if (hi > NN) hi = NN;
    int s = 0;
    for (int i = lo; i < hi; ++i) s += deg[i];
    sums[t] = s;
    __syncthreads();
    // Hillis-Steele inclusive scan (read phase / barrier / write phase)
    for (int off = 1; off < 1024; off <<= 1) {
        int v = (t >= off) ? sums[t - off] : 0;
        __syncthreads();
        if (t >= off) sums[t] += v;
        __syncthreads();
    }
    int base = (t == 0) ? 0 : sums[t - 1];
    for (int i = lo; i < hi; ++i) {
        row_ptr[i] = base;
        cursor[i]  = base;
        base += deg[i];
    }
    if (t == 1023) row_ptr[NN] = base;   // == NE
}

// ---- fill: eidx[pos] = src, grouped by dst ----
__global__ void fill_kernel(const int* __restrict__ ei, int* __restrict__ cursor,
                            int* __restrict__ eidx) {
    int e = blockIdx.x * blockDim.x + threadIdx.x;
    if (e >= NE) return;
    int src = ei[e];
    int dst = ei[NE + e];
    int pos = atomicAdd(&cursor[dst], 1);
    eidx[pos] = src;
}

// ---- gather: m[i] = sum_{e in CSR row i} x[eidx[e]] ; half-wave (32 lanes) per node ----
__global__ void gather_kernel(const float* __restrict__ x, const int* __restrict__ row_ptr,
                              const int* __restrict__ eidx, float* __restrict__ m) {
    int t = blockIdx.x * blockDim.x + threadIdx.x;
    int node = t >> 5;
    int j = (t & 31) * 4;
    if (node >= NN) return;
    int beg = row_ptr[node], end = row_ptr[node + 1];
    float4 acc = {0.f, 0.f, 0.f, 0.f};
    for (int e = beg; e < end; ++e) {
        int src = eidx[e];
        float4 v = *(const float4*)(x + (size_t)src * DD + j);
        acc.x += v.x; acc.y += v.y; acc.z += v.z; acc.w += v.w;
    }
    *(float4*)(m + (size_t)node * DD + j) = acc;
}

// Fused: h0 = x + m; h1 = relu(h0@W1+b1); h = h1@W2+b2; out = LN(h)*gamma+beta
// Block = 256 threads (4 waves), 64 nodes/block, wave w owns rows [blk*64+w*16, +16).
// MFMA 16x16x32 bf16. C/D: col = lane&15, row = (lane>>4)*4 + reg.
__launch_bounds__(256)
__global__ void fused_mlp_ln_kernel(const float* __restrict__ x, const float* __restrict__ m,
                                    const unsigned short* __restrict__ w1t,
                                    const unsigned short* __restrict__ w2t,
                                    const float* __restrict__ b1, const float* __restrict__ b2,
                                    const float* __restrict__ gamma, const float* __restrict__ beta,
                                    float* __restrict__ out) {
    __shared__ __align__(16) unsigned short h1[4][16][136];

    const int tid  = threadIdx.x;
    const int w    = tid >> 6;
    const int l    = tid & 63;
    const int lcol = l & 15;
    const int g    = l >> 4;
    const int m0   = blockIdx.x * 64 + w * 16;

    int arow = m0 + lcol;
    if (arow >= NN) arow = NN - 1;
    const float* xr = x + (size_t)arow * DD;
    const float* mr = m + (size_t)arow * DD;
    bf16x8 afrag[4];
    #pragma unroll
    for (int t = 0; t < 4; ++t) {
        int k0 = t * 32 + g * 8;
        float4 xa = *(const float4*)(xr + k0);
        float4 xb = *(const float4*)(xr + k0 + 4);
        float4 ma = *(const float4*)(mr + k0);
        float4 mb = *(const float4*)(mr + k0 + 4);
        bf16x8 a;
        a[0] = (__bf16)(xa.x + ma.x); a[1] = (__bf16)(xa.y + ma.y);
        a[2] = (__bf16)(xa.z + ma.z); a[3] = (__bf16)(xa.w + ma.w);
        a[4] = (__bf16)(xb.x + mb.x); a[5] = (__bf16)(xb.y + mb.y);
        a[6] = (__bf16)(xb.z + mb.z); a[7] = (__bf16)(xb.w + mb.w);
        afrag[t] = a;
    }

    f32x4 acc[8];
    #pragma unroll
    for (int nt = 0; nt < 8; ++nt) {
        float bv = b1[nt * 16 + lcol];
        acc[nt] = (f32x4){bv, bv, bv, bv};
    }
    #pragma unroll
    for (int t = 0; t < 4; ++t) {
        int k0 = t * 32 + g * 8;
        #pragma unroll
        for (int nt = 0; nt < 8; ++nt) {
            ushort8 bu = *(const ushort8*)(w1t + (size_t)(nt * 16 + lcol) * DD + k0);
            acc[nt] = __builtin_amdgcn_mfma_f32_16x16x32_bf16(
                afrag[t], __builtin_bit_cast(bf16x8, bu), acc[nt], 0, 0, 0);
        }
    }

    #pragma unroll
    for (int nt = 0; nt < 8; ++nt)
        #pragma unroll
        for (int r = 0; r < 4; ++r) {
            float v = fmaxf(acc[nt][r], 0.f);
            h1[w][g * 4 + r][nt * 16 + lcol] = f2bf(v);
        }
    __syncthreads();

    bf16x8 a2[4];
    #pragma unroll
    for (int t = 0; t < 4; ++t) {
        int k0 = t * 32 + g * 8;
        a2[t] = __builtin_bit_cast(bf16x8, *(const ushort8*)(&h1[w][lcol][k0]));
    }

    #pragma unroll
    for (int nt = 0; nt < 8; ++nt) {
        float bv = b2[nt * 16 + lcol];
        acc[nt] = (f32x4){bv, bv, bv, bv};
    }
    #pragma unroll
    for (int t = 0; t < 4; ++t) {
        #pragma unroll
        for (int nt = 0; nt < 8; ++nt) {
            ushort8 bu = *(const ushort8*)(w2t + (size_t)(nt * 16 + lcol) * DD + (t * 32 + g * 8));
            acc[nt] = __builtin_amdgcn_mfma_f32_16x16x32_bf16(
                a2[t], __builtin_bit_cast(bf16x8, bu), acc[nt], 0, 0, 0);
        }
    }

    float gmm[8], bta[8];
    #pragma unroll
    for (int nt = 0; nt < 8; ++nt) {
        gmm[nt] = gamma[nt * 16 + lcol];
        bta[nt] = beta[nt * 16 + lcol];
    }
    #pragma unroll
    for (int r = 0; r < 4; ++r) {
        int row = m0 + g * 4 + r;
        float s = 0.f, s2 = 0.f;
        #pragma unroll
        for (int nt = 0; nt < 8; ++nt) {
            float v = acc[nt][r];
            s += v; s2 += v * v;
        }
        #pragma unroll
        for (int msk = 1; msk < 16; msk <<= 1) {
            s  += __shfl_xor(s,  msk);
            s2 += __shfl_xor(s2, msk);
        }
        float mu  = s * (1.f / 128.f);
        float var = s2 * (1.f / 128.f) - mu * mu;
        float rs  = rsqrtf(var + 1e-5f);
        if (row < NN) {
            float* op = out + (size_t)row * DD;
            #pragma unroll
            for (int nt = 0; nt < 8; ++nt)
                op[nt * 16 + lcol] = (acc[nt][r] - mu) * rs * gmm[nt] + bta[nt];
        }
    }
}

extern "C" void kernel_launch(void* const* d_in, const int* in_sizes, int n_in,
                              void* d_out, int out_size, void* d_ws, size_t ws_size,
                              hipStream_t stream) {
    const float* x     = (const float*)d_in[0];
    const float* W1    = (const float*)d_in[1];
    const float* b1    = (const float*)d_in[2];
    const float* W2    = (const float*)d_in[3];
    const float* b2    = (const float*)d_in[4];
    const float* gamma = (const float*)d_in[5];
    const float* beta  = (const float*)d_in[6];
    const int*   ei    = (const int*)d_in[7];
    float* out = (float*)d_out;

    // ws layout: m | w1t | w2t | deg | cursor | row_ptr | eidx
    char* base = (char*)d_ws;
    float* m = (float*)base;                      base += (size_t)NN * DD * sizeof(float);
    unsigned short* w1t = (unsigned short*)base;  base += DD * DD * sizeof(unsigned short);
    unsigned short* w2t = (unsigned short*)base;  base += DD * DD * sizeof(unsigned short);
    int* deg     = (int*)base;                    base += NN * sizeof(int);
    int* cursor  = (int*)base;                    base += NN * sizeof(int);
    int* row_ptr = (int*)base;                    base += (NN + 1) * sizeof(int);
    int* eidx    = (int*)base;                    base += NE * sizeof(int);

    hipMemsetAsync(deg, 0, NN * sizeof(int), stream);
    prep_w_kernel<<<(DD * DD) / 256, 256, 0, stream>>>(W1, W2, w1t, w2t);
    hist_kernel<<<(NE + 255) / 256, 256, 0, stream>>>(ei, deg);
    scan_kernel<<<1, 1024, 0, stream>>>(deg, row_ptr, cursor);
    fill_kernel<<<(NE + 255) / 256, 256, 0, stream>>>(ei, cursor, eidx);
    gather_kernel<<<(NN * 32 + 255) / 256, 256, 0, stream>>>(x, row_ptr, eidx, m);
    fused_mlp_ln_kernel<<<(NN + 63) / 64, 256, 0, stream>>>(
        x, m, w1t, w2t, b1, b2, gamma, beta, out);
}

// Round 6
// 292.737 us; speedup vs baseline: 4.0348x; 1.7403x over previous
//
#include <hip/hip_runtime.h>

#define NN 100000
#define NE 600000
#define DD 128
#define SCAN_BLOCKS 100
#define SCAN_CHUNK  1000   // SCAN_BLOCKS * SCAN_CHUNK == NN exactly

typedef __bf16 bf16x8 __attribute__((ext_vector_type(8)));
typedef float f32x4 __attribute__((ext_vector_type(4)));
typedef unsigned short ushort8 __attribute__((ext_vector_type(8)));

static __device__ __forceinline__ unsigned short f2bf(float f) {
    return __builtin_bit_cast(unsigned short, (__bf16)f);
}

// Transpose W1/W2 into ws as bf16: wt[n][k] = W[k][n]
__global__ void prep_w_kernel(const float* __restrict__ W1, const float* __restrict__ W2,
                              unsigned short* __restrict__ w1t, unsigned short* __restrict__ w2t) {
    int t = blockIdx.x * blockDim.x + threadIdx.x;   // 16384 threads
    int k = t >> 7, n = t & 127;
    w1t[n * DD + k] = f2bf(W1[k * DD + n]);
    w2t[n * DD + k] = f2bf(W2[k * DD + n]);
}

// ---- CSR build: histogram of dst degrees ----
__global__ void hist_kernel(const int* __restrict__ ei, int* __restrict__ deg) {
    int e = blockIdx.x * blockDim.x + threadIdx.x;
    if (e < NE) atomicAdd(&deg[ei[NE + e]], 1);
}

// ---- hierarchical scan: A) per-block reduce ----
__global__ void scanA_kernel(const int* __restrict__ deg, int* __restrict__ bsum) {
    __shared__ int red[256];
    int b = blockIdx.x, t = threadIdx.x;
    int base = b * SCAN_CHUNK;
    int s = 0;
    for (int i = t; i < SCAN_CHUNK; i += 256) s += deg[base + i];
    red[t] = s;
    __syncthreads();
    for (int off = 128; off > 0; off >>= 1) {
        if (t < off) red[t] += red[t + off];
        __syncthreads();
    }
    if (t == 0) bsum[b] = red[0];
}

// ---- B) exclusive scan of 100 block sums (1 block, 128 thr) ----
__global__ void scanB_kernel(const int* __restrict__ bsum, int* __restrict__ boff) {
    __shared__ int s[128];
    int t = threadIdx.x;
    int v0 = (t < SCAN_BLOCKS) ? bsum[t] : 0;
    s[t] = v0;
    __syncthreads();
    for (int off = 1; off < 128; off <<= 1) {
        int u = (t >= off) ? s[t - off] : 0;
        __syncthreads();
        s[t] += u;
        __syncthreads();
    }
    if (t < SCAN_BLOCKS) boff[t] = s[t] - v0;   // exclusive
}

// ---- C) per-block coalesced scan -> row_ptr + cursor ----
__global__ void scanC_kernel(const int* __restrict__ deg, const int* __restrict__ boff,
                             int* __restrict__ row_ptr, int* __restrict__ cursor) {
    __shared__ int s[1024];
    int b = blockIdx.x, t = threadIdx.x;
    int i = b * SCAN_CHUNK + t;
    int v = (t < SCAN_CHUNK) ? deg[i] : 0;
    s[t] = v;
    __syncthreads();
    for (int off = 1; off < 1024; off <<= 1) {
        int u = (t >= off) ? s[t - off] : 0;
        __syncthreads();
        s[t] += u;
        __syncthreads();
    }
    if (t < SCAN_CHUNK) {
        int excl = boff[b] + s[t] - v;
        row_ptr[i] = excl;
        cursor[i]  = excl;
        if (i == NN - 1) row_ptr[NN] = excl + v;   // == NE
    }
}

// ---- fill: eidx[pos] = src, grouped by dst ----
__global__ void fill_kernel(const int* __restrict__ ei, int* __restrict__ cursor,
                            int* __restrict__ eidx) {
    int e = blockIdx.x * blockDim.x + threadIdx.x;
    if (e >= NE) return;
    int src = ei[e];
    int dst = ei[NE + e];
    int pos = atomicAdd(&cursor[dst], 1);
    eidx[pos] = src;
}

// ---- gather: m[i] = sum_{e in CSR row i} x[eidx[e]] ; half-wave (32 lanes) per node ----
__global__ void gather_kernel(const float* __restrict__ x, const int* __restrict__ row_ptr,
                              const int* __restrict__ eidx, float* __restrict__ m) {
    int t = blockIdx.x * blockDim.x + threadIdx.x;
    int node = t >> 5;
    int j = (t & 31) * 4;
    if (node >= NN) return;
    int beg = row_ptr[node], end = row_ptr[node + 1];
    float4 acc = {0.f, 0.f, 0.f, 0.f};
    for (int e = beg; e < end; ++e) {
        int src = eidx[e];
        float4 v = *(const float4*)(x + (size_t)src * DD + j);
        acc.x += v.x; acc.y += v.y; acc.z += v.z; acc.w += v.w;
    }
    *(float4*)(m + (size_t)node * DD + j) = acc;
}

// Fused: h0 = x + m; h1 = relu(h0@W1+b1); h = h1@W2+b2; out = LN(h)*gamma+beta
// Block = 256 threads (4 waves), 64 nodes/block, wave w owns rows [blk*64+w*16, +16).
// MFMA 16x16x32 bf16. C/D: col = lane&15, row = (lane>>4)*4 + reg.
__launch_bounds__(256)
__global__ void fused_mlp_ln_kernel(const float* __restrict__ x, const float* __restrict__ m,
                                    const unsigned short* __restrict__ w1t,
                                    const unsigned short* __restrict__ w2t,
                                    const float* __restrict__ b1, const float* __restrict__ b2,
                                    const float* __restrict__ gamma, const float* __restrict__ beta,
                                    float* __restrict__ out) {
    __shared__ __align__(16) unsigned short h1[4][16][136];

    const int tid  = threadIdx.x;
    const int w    = tid >> 6;
    const int l    = tid & 63;
    const int lcol = l & 15;
    const int g    = l >> 4;
    const int m0   = blockIdx.x * 64 + w * 16;

    int arow = m0 + lcol;
    if (arow >= NN) arow = NN - 1;
    const float* xr = x + (size_t)arow * DD;
    const float* mr = m + (size_t)arow * DD;
    bf16x8 afrag[4];
    #pragma unroll
    for (int t = 0; t < 4; ++t) {
        int k0 = t * 32 + g * 8;
        float4 xa = *(const float4*)(xr + k0);
        float4 xb = *(const float4*)(xr + k0 + 4);
        float4 ma = *(const float4*)(mr + k0);
        float4 mb = *(const float4*)(mr + k0 + 4);
        bf16x8 a;
        a[0] = (__bf16)(xa.x + ma.x); a[1] = (__bf16)(xa.y + ma.y);
        a[2] = (__bf16)(xa.z + ma.z); a[3] = (__bf16)(xa.w + ma.w);
        a[4] = (__bf16)(xb.x + mb.x); a[5] = (__bf16)(xb.y + mb.y);
        a[6] = (__bf16)(xb.z + mb.z); a[7] = (__bf16)(xb.w + mb.w);
        afrag[t] = a;
    }

    f32x4 acc[8];
    #pragma unroll
    for (int nt = 0; nt < 8; ++nt) {
        float bv = b1[nt * 16 + lcol];
        acc[nt] = (f32x4){bv, bv, bv, bv};
    }
    #pragma unroll
    for (int t = 0; t < 4; ++t) {
        int k0 = t * 32 + g * 8;
        #pragma unroll
        for (int nt = 0; nt < 8; ++nt) {
            ushort8 bu = *(const ushort8*)(w1t + (size_t)(nt * 16 + lcol) * DD + k0);
            acc[nt] = __builtin_amdgcn_mfma_f32_16x16x32_bf16(
                afrag[t], __builtin_bit_cast(bf16x8, bu), acc[nt], 0, 0, 0);
        }
    }

    #pragma unroll
    for (int nt = 0; nt < 8; ++nt)
        #pragma unroll
        for (int r = 0; r < 4; ++r) {
            float v = fmaxf(acc[nt][r], 0.f);
            h1[w][g * 4 + r][nt * 16 + lcol] = f2bf(v);
        }
    __syncthreads();

    bf16x8 a2[4];
    #pragma unroll
    for (int t = 0; t < 4; ++t) {
        int k0 = t * 32 + g * 8;
        a2[t] = __builtin_bit_cast(bf16x8, *(const ushort8*)(&h1[w][lcol][k0]));
    }

    #pragma unroll
    for (int nt = 0; nt < 8; ++nt) {
        float bv = b2[nt * 16 + lcol];
        acc[nt] = (f32x4){bv, bv, bv, bv};
    }
    #pragma unroll
    for (int t = 0; t < 4; ++t) {
        #pragma unroll
        for (int nt = 0; nt < 8; ++nt) {
            ushort8 bu = *(const ushort8*)(w2t + (size_t)(nt * 16 + lcol) * DD + (t * 32 + g * 8));
            acc[nt] = __builtin_amdgcn_mfma_f32_16x16x32_bf16(
                a2[t], __builtin_bit_cast(bf16x8, bu), acc[nt], 0, 0, 0);
        }
    }

    float gmm[8], bta[8];
    #pragma unroll
    for (int nt = 0; nt < 8; ++nt) {
        gmm[nt] = gamma[nt * 16 + lcol];
        bta[nt] = beta[nt * 16 + lcol];
    }
    #pragma unroll
    for (int r = 0; r < 4; ++r) {
        int row = m0 + g * 4 + r;
        float s = 0.f, s2 = 0.f;
        #pragma unroll
        for (int nt = 0; nt < 8; ++nt) {
            float v = acc[nt][r];
            s += v; s2 += v * v;
        }
        #pragma unroll
        for (int msk = 1; msk < 16; msk <<= 1) {
            s  += __shfl_xor(s,  msk);
            s2 += __shfl_xor(s2, msk);
        }
        float mu  = s * (1.f / 128.f);
        float var = s2 * (1.f / 128.f) - mu * mu;
        float rs  = rsqrtf(var + 1e-5f);
        if (row < NN) {
            float* op = out + (size_t)row * DD;
            #pragma unroll
            for (int nt = 0; nt < 8; ++nt)
                op[nt * 16 + lcol] = (acc[nt][r] - mu) * rs * gmm[nt] + bta[nt];
        }
    }
}

extern "C" void kernel_launch(void* const* d_in, const int* in_sizes, int n_in,
                              void* d_out, int out_size, void* d_ws, size_t ws_size,
                              hipStream_t stream) {
    const float* x     = (const float*)d_in[0];
    const float* W1    = (const float*)d_in[1];
    const float* b1    = (const float*)d_in[2];
    const float* W2    = (const float*)d_in[3];
    const float* b2    = (const float*)d_in[4];
    const float* gamma = (const float*)d_in[5];
    const float* beta  = (const float*)d_in[6];
    const int*   ei    = (const int*)d_in[7];
    float* out = (float*)d_out;

    // ws layout: m | w1t | w2t | deg | cursor | row_ptr | eidx | bsum | boff
    char* base = (char*)d_ws;
    float* m = (float*)base;                      base += (size_t)NN * DD * sizeof(float);
    unsigned short* w1t = (unsigned short*)base;  base += DD * DD * sizeof(unsigned short);
    unsigned short* w2t = (unsigned short*)base;  base += DD * DD * sizeof(unsigned short);
    int* deg     = (int*)base;                    base += NN * sizeof(int);
    int* cursor  = (int*)base;                    base += NN * sizeof(int);
    int* row_ptr = (int*)base;                    base += (NN + 1) * sizeof(int);
    int* eidx    = (int*)base;                    base += NE * sizeof(int);
    int* bsum    = (int*)base;                    base += 128 * sizeof(int);
    int* boff    = (int*)base;                    base += 128 * sizeof(int);

    hipMemsetAsync(deg, 0, NN * sizeof(int), stream);
    prep_w_kernel<<<(DD * DD) / 256, 256, 0, stream>>>(W1, W2, w1t, w2t);
    hist_kernel<<<(NE + 255) / 256, 256, 0, stream>>>(ei, deg);
    scanA_kernel<<<SCAN_BLOCKS, 256, 0, stream>>>(deg, bsum);
    scanB_kernel<<<1, 128, 0, stream>>>(bsum, boff);
    scanC_kernel<<<SCAN_BLOCKS, 1024, 0, stream>>>(deg, boff, row_ptr, cursor);
    fill_kernel<<<(NE + 255) / 256, 256, 0, stream>>>(ei, cursor, eidx);
    gather_kernel<<<(NN * 32 + 255) / 256, 256, 0, stream>>>(x, row_ptr, eidx, m);
    fused_mlp_ln_kernel<<<(NN + 63) / 64, 256, 0, stream>>>(
        x, m, w1t, w2t, b1, b2, gamma, beta, out);
}